// Round 1
// baseline (517.950 us; speedup 1.0000x reference)
//
#include <hip/hip_runtime.h>
#include <hip/hip_cooperative_groups.h>
#include <math.h>

namespace cg = cooperative_groups;

// Problem constants (from reference)
#define B_  64
#define S_  2048
#define E_  300
#define H_  150
#define C_  34
#define CHUNK 128
#define NCHUNK (S_ / CHUNK)   // 16
#define WAVES 4               // 256-thread blocks

// ---------------------------------------------------------------------------
// Shared attention chunk pass (identical math to the verified attn_pass):
// wave w handles tokens w+4k of its 128-token chunk, groups of 4 tokens,
// 8 row loads in flight, interleaved butterfly reduces, branchless grouped
// online-softmax rescale. Block combines 4 waves via LDS and writes per-chunk
// (m, l, unnormalized h[300]).
// ---------------------------------------------------------------------------
__device__ __forceinline__ void attn_chunk(
    const int* __restrict__ x, const float* __restrict__ emb,
    const float* __restrict__ qmat, int q_stride, float scale,
    float* __restrict__ h_part, float* __restrict__ m_part,
    float* __restrict__ l_part, int b, int chunk, int tid,
    float* sm, float* sl, float (*sacc)[304])
{
    const int w    = tid >> 6;
    const int lane = tid & 63;

    // Per-lane query fragment (pre-scaled): float4 slot `lane` + slot 64+lane
    const float4* qp = (const float4*)(qmat + (size_t)b * q_stride);
    float4 q0 = qp[lane];
    float4 q1 = make_float4(0.f, 0.f, 0.f, 0.f);
    if (lane < 11) q1 = qp[64 + lane];
    q0.x *= scale; q0.y *= scale; q0.z *= scale; q0.w *= scale;
    q1.x *= scale; q1.y *= scale; q1.z *= scale; q1.w *= scale;

    // Wave's 32 token indices live in lanes 0..31
    const int base = b * S_ + chunk * CHUNK;
    int myidx = 0;
    if (lane < 32) myidx = x[base + w + 4 * lane];

    float  m = -INFINITY, l = 0.f;
    float4 a0 = make_float4(0.f, 0.f, 0.f, 0.f);
    float4 a1 = make_float4(0.f, 0.f, 0.f, 0.f);

    for (int g = 0; g < 8; ++g) {
        // --- 8 independent loads in flight ---
        float4 r0[4], r1[4];
        #pragma unroll
        for (int t = 0; t < 4; ++t) {
            const int row = __shfl(myidx, 4 * g + t);
            const float4* rp = (const float4*)(emb + (size_t)row * E_);
            r0[t] = rp[lane];
            r1[t] = make_float4(0.f, 0.f, 0.f, 0.f);
            if (lane < 11) r1[t] = rp[64 + lane];
        }
        // --- 4 dots ---
        float d[4];
        #pragma unroll
        for (int t = 0; t < 4; ++t)
            d[t] = q0.x * r0[t].x + q0.y * r0[t].y + q0.z * r0[t].z + q0.w * r0[t].w
                 + q1.x * r1[t].x + q1.y * r1[t].y + q1.z * r1[t].z + q1.w * r1[t].w;
        // --- 4 butterfly reduces, interleaved (independent DS chains) ---
        #pragma unroll
        for (int off = 32; off > 0; off >>= 1) {
            #pragma unroll
            for (int t = 0; t < 4; ++t) d[t] += __shfl_xor(d[t], off);
        }
        // --- branchless grouped online-softmax update ---
        const float gm = fmaxf(fmaxf(d[0], d[1]), fmaxf(d[2], d[3]));
        const float mn = fmaxf(m, gm);
        const float c  = __expf(m - mn);        // first group: exp(-inf)=0
        const float p0 = __expf(d[0] - mn), p1 = __expf(d[1] - mn);
        const float p2 = __expf(d[2] - mn), p3 = __expf(d[3] - mn);
        l = l * c + ((p0 + p1) + (p2 + p3));
        a0.x = a0.x * c + p0 * r0[0].x + p1 * r0[1].x + p2 * r0[2].x + p3 * r0[3].x;
        a0.y = a0.y * c + p0 * r0[0].y + p1 * r0[1].y + p2 * r0[2].y + p3 * r0[3].y;
        a0.z = a0.z * c + p0 * r0[0].z + p1 * r0[1].z + p2 * r0[2].z + p3 * r0[3].z;
        a0.w = a0.w * c + p0 * r0[0].w + p1 * r0[1].w + p2 * r0[2].w + p3 * r0[3].w;
        a1.x = a1.x * c + p0 * r1[0].x + p1 * r1[1].x + p2 * r1[2].x + p3 * r1[3].x;
        a1.y = a1.y * c + p0 * r1[0].y + p1 * r1[1].y + p2 * r1[2].y + p3 * r1[3].y;
        a1.z = a1.z * c + p0 * r1[0].z + p1 * r1[1].z + p2 * r1[2].z + p3 * r1[3].z;
        a1.w = a1.w * c + p0 * r1[0].w + p1 * r1[1].w + p2 * r1[2].w + p3 * r1[3].w;
        m = mn;
    }

    // Combine 4 waves in LDS
    ((float4*)sacc[w])[lane] = a0;
    if (lane < 11) ((float4*)sacc[w])[64 + lane] = a1;
    if (lane == 0) { sm[w] = m; sl[w] = l; }
    __syncthreads();

    const float mb = fmaxf(fmaxf(sm[0], sm[1]), fmaxf(sm[2], sm[3]));
    const int pi = b * NCHUNK + chunk;
    for (int j = tid; j < E_; j += 256) {
        float h = 0.f;
        #pragma unroll
        for (int c2 = 0; c2 < WAVES; ++c2)
            h += __expf(sm[c2] - mb) * sacc[c2][j];
        h_part[(size_t)pi * E_ + j] = h;
    }
    if (tid == 0) {
        float lb = 0.f;
        #pragma unroll
        for (int c2 = 0; c2 < WAVES; ++c2) lb += __expf(sm[c2] - mb) * sl[c2];
        m_part[pi] = mb; l_part[pi] = lb;
    }
    __syncthreads();
}

// ---------------------------------------------------------------------------
// Fused cooperative kernel: A) pass-1 attn  B) h1 + v2=(h1@W)@W^T
//                           C) pass-2 attn  D) h2 + scores
// Grid 16x64 = 1024 blocks x 256 thr; 4 blocks/CU -> exactly co-resident.
// ---------------------------------------------------------------------------
__global__ __launch_bounds__(256, 4) void fused(
    const int* __restrict__ x, const float* __restrict__ emb,
    const float* __restrict__ query, const float* __restrict__ Watt,
    const float* __restrict__ Wout, const float* __restrict__ bias,
    float* __restrict__ out,
    float* __restrict__ h_part, float* __restrict__ m_part,
    float* __restrict__ l_part, float* __restrict__ h1,
    float* __restrict__ v2)
{
    const int chunk = blockIdx.x, b = blockIdx.y, tid = threadIdx.x;
    cg::grid_group grid = cg::this_grid();

    __shared__ float sm4[WAVES], sl4[WAVES];
    __shared__ __align__(16) float sacc[WAVES][304];
    __shared__ float smc[NCHUNK], slc[NCHUNK];
    __shared__ float sh[E_];      // stage B: h1 row
    __shared__ float sq[H_];      // stage B: h1 @ W
    __shared__ float hh[2 * E_];  // stage D: [h1; h2]

    const float scale1 = 0.0577350269189626f;  // 1/sqrt(300)

    // ---- Stage A: pass-1 attention (query broadcast, stride 0) ----
    attn_chunk(x, emb, query, 0, scale1, h_part, m_part, l_part,
               b, chunk, tid, sm4, sl4, sacc);
    grid.sync();

    // ---- Stage B: combine partials -> h1[b]; v2[b] = (h1 @ W) @ W^T ----
    if (chunk == 0) {
        if (tid < NCHUNK) { smc[tid] = m_part[b * NCHUNK + tid];
                            slc[tid] = l_part[b * NCHUNK + tid]; }
        __syncthreads();
        float M = -INFINITY;
        #pragma unroll
        for (int c = 0; c < NCHUNK; ++c) M = fmaxf(M, smc[c]);
        float L = 0.f;
        #pragma unroll
        for (int c = 0; c < NCHUNK; ++c) L += __expf(smc[c] - M) * slc[c];
        for (int j = tid; j < E_; j += 256) {
            float h = 0.f;
            #pragma unroll
            for (int c = 0; c < NCHUNK; ++c)
                h += __expf(smc[c] - M) * h_part[((size_t)b * NCHUNK + c) * E_ + j];
            const float v = h / L;
            sh[j] = v;
            h1[b * E_ + j] = v;
        }
        __syncthreads();
        if (tid < H_) {
            float acc = 0.f;
            for (int e = 0; e < E_; ++e) acc += sh[e] * Watt[e * H_ + tid];
            sq[tid] = acc;
        }
        __syncthreads();
        for (int j = tid; j < E_; j += 256) {
            float acc = 0.f;
            const float* wr = Watt + (size_t)j * H_;
            for (int h = 0; h < H_; ++h) acc += sq[h] * wr[h];
            v2[b * E_ + j] = acc;
        }
    }
    grid.sync();

    // ---- Stage C: pass-2 attention (query v2[b], stride E, no scale) ----
    attn_chunk(x, emb, v2, E_, 1.0f, h_part, m_part, l_part,
               b, chunk, tid, sm4, sl4, sacc);
    grid.sync();

    // ---- Stage D: combine partials -> h2; scores = [h1;h2]@Wout + bias ----
    if (chunk == 0) {
        if (tid < NCHUNK) { smc[tid] = m_part[b * NCHUNK + tid];
                            slc[tid] = l_part[b * NCHUNK + tid]; }
        for (int j = tid; j < E_; j += 256) hh[j] = h1[b * E_ + j];
        __syncthreads();
        float M = -INFINITY;
        #pragma unroll
        for (int c = 0; c < NCHUNK; ++c) M = fmaxf(M, smc[c]);
        float L = 0.f;
        #pragma unroll
        for (int c = 0; c < NCHUNK; ++c) L += __expf(smc[c] - M) * slc[c];
        for (int j = tid; j < E_; j += 256) {
            float h = 0.f;
            #pragma unroll
            for (int c = 0; c < NCHUNK; ++c)
                h += __expf(smc[c] - M) * h_part[((size_t)b * NCHUNK + c) * E_ + j];
            hh[E_ + j] = h / L;
        }
        __syncthreads();
        const int w = tid >> 6, lane = tid & 63;
        for (int c = w; c < C_; c += 4) {   // 4 waves cover 34 classes
            float p = 0.f;
            for (int e = lane; e < 2 * E_; e += 64)
                p += hh[e] * Wout[(size_t)e * C_ + c];
            #pragma unroll
            for (int off = 32; off > 0; off >>= 1) p += __shfl_xor(p, off);
            if (lane == 0) out[b * C_ + c] = p + bias[c];
        }
    }
}

// ---------------------------------------------------------------------------
// Fallback path: the verified 4-kernel pipeline (unchanged), used only if
// hipLaunchCooperativeKernel is rejected (e.g. by graph capture).
// ---------------------------------------------------------------------------
__global__ __launch_bounds__(256, 4) void attn_pass(
    const int* __restrict__ x, const float* __restrict__ emb,
    const float* __restrict__ qmat, int q_stride, float scale,
    float* __restrict__ h_part, float* __restrict__ m_part,
    float* __restrict__ l_part)
{
    __shared__ float sm[WAVES], sl[WAVES];
    __shared__ __align__(16) float sacc[WAVES][304];
    attn_chunk(x, emb, qmat, q_stride, scale, h_part, m_part, l_part,
               blockIdx.y, blockIdx.x, threadIdx.x, sm, sl, sacc);
}

__global__ __launch_bounds__(320) void combine_qv(
    const float* __restrict__ h_part, const float* __restrict__ m_part,
    const float* __restrict__ l_part, const float* __restrict__ W,
    float* __restrict__ h1out, float* __restrict__ v2out)
{
    const int b = blockIdx.x, tid = threadIdx.x;
    __shared__ float sm[NCHUNK], sl[NCHUNK], sh[E_], sq[H_];
    if (tid < NCHUNK) { sm[tid] = m_part[b * NCHUNK + tid];
                        sl[tid] = l_part[b * NCHUNK + tid]; }
    __syncthreads();
    if (tid < E_) {
        float M = -INFINITY;
        #pragma unroll
        for (int c = 0; c < NCHUNK; ++c) M = fmaxf(M, sm[c]);
        float L = 0.f, h = 0.f;
        #pragma unroll
        for (int c = 0; c < NCHUNK; ++c) {
            const float wc = __expf(sm[c] - M);
            L += wc * sl[c];
            h += wc * h_part[((size_t)b * NCHUNK + c) * E_ + tid];
        }
        const float v = h / L;
        sh[tid] = v;
        h1out[b * E_ + tid] = v;
    }
    __syncthreads();
    if (tid < H_) {
        float acc = 0.f;
        for (int e = 0; e < E_; ++e) acc += sh[e] * W[e * H_ + tid];
        sq[tid] = acc;
    }
    __syncthreads();
    if (tid < E_) {
        float acc = 0.f;
        const float* wr = W + (size_t)tid * H_;
        for (int h = 0; h < H_; ++h) acc += sq[h] * wr[h];
        v2out[b * E_ + tid] = acc;
    }
}

__global__ __launch_bounds__(320) void combine_scores(
    const float* __restrict__ h_part, const float* __restrict__ m_part,
    const float* __restrict__ l_part, const float* __restrict__ h1,
    const float* __restrict__ Wout, const float* __restrict__ bias,
    float* __restrict__ out)
{
    const int b = blockIdx.x, tid = threadIdx.x;
    const int w = tid >> 6, lane = tid & 63;
    __shared__ float sm[NCHUNK], sl[NCHUNK];
    __shared__ float hh[2 * E_];
    if (tid < NCHUNK) { sm[tid] = m_part[b * NCHUNK + tid];
                        sl[tid] = l_part[b * NCHUNK + tid]; }
    if (tid < E_) hh[tid] = h1[b * E_ + tid];
    __syncthreads();
    if (tid < E_) {
        float M = -INFINITY;
        #pragma unroll
        for (int c = 0; c < NCHUNK; ++c) M = fmaxf(M, sm[c]);
        float L = 0.f, h = 0.f;
        #pragma unroll
        for (int c = 0; c < NCHUNK; ++c) {
            const float wc = __expf(sm[c] - M);
            L += wc * sl[c];
            h += wc * h_part[((size_t)b * NCHUNK + c) * E_ + tid];
        }
        hh[E_ + tid] = h / L;
    }
    __syncthreads();
    for (int c = w; c < C_; c += 5) {
        float p = 0.f;
        for (int e = lane; e < 2 * E_; e += 64)
            p += hh[e] * Wout[(size_t)e * C_ + c];
        #pragma unroll
        for (int off = 32; off > 0; off >>= 1) p += __shfl_xor(p, off);
        if (lane == 0) out[b * C_ + c] = p + bias[c];
    }
}

extern "C" void kernel_launch(void* const* d_in, const int* in_sizes, int n_in,
                              void* d_out, int out_size, void* d_ws, size_t ws_size,
                              hipStream_t stream) {
    const int*   x     = (const int*)  d_in[0];   // [64,2048] int32
    const float* emb   = (const float*)d_in[1];   // [50000,300]
    const float* query = (const float*)d_in[2];   // [1,300]
    const float* Watt  = (const float*)d_in[3];   // [300,150]
    const float* Wout  = (const float*)d_in[4];   // [600,34]
    const float* bias  = (const float*)d_in[5];   // [34]
    float* out = (float*)d_out;                   // [64,34]

    // Workspace layout (floats)
    float* ws     = (float*)d_ws;
    float* h_part = ws;                                 // B*NCHUNK*E = 307200
    float* m_part = h_part + (size_t)B_ * NCHUNK * E_;  // 1024
    float* l_part = m_part + B_ * NCHUNK;               // 1024
    float* h1     = l_part + B_ * NCHUNK;               // 19200
    float* v2     = h1 + B_ * E_;                       // 19200

    dim3 grid(NCHUNK, B_), blk(256);

    void* args[] = {
        (void*)&x, (void*)&emb, (void*)&query, (void*)&Watt, (void*)&Wout,
        (void*)&bias, (void*)&out, (void*)&h_part, (void*)&m_part,
        (void*)&l_part, (void*)&h1, (void*)&v2
    };
    hipError_t err = hipLaunchCooperativeKernel((const void*)fused, grid, blk,
                                                args, 0, stream);
    if (err != hipSuccess) {
        // Fallback: proven 4-kernel pipeline (169.9 us)
        const float scale1 = 1.0f / sqrtf((float)E_);
        attn_pass<<<grid, blk, 0, stream>>>(x, emb, query, 0, scale1,
                                            h_part, m_part, l_part);
        combine_qv<<<B_, 320, 0, stream>>>(h_part, m_part, l_part, Watt, h1, v2);
        attn_pass<<<grid, blk, 0, stream>>>(x, emb, v2, E_, 1.0f,
                                            h_part, m_part, l_part);
        combine_scores<<<B_, 320, 0, stream>>>(h_part, m_part, l_part, h1,
                                               Wout, bias, out);
    }
}

// Round 2
// 397.991 us; speedup vs baseline: 1.3014x; 1.3014x over previous
//
#include <hip/hip_runtime.h>
#include <math.h>

// Problem constants (from reference)
#define B_  64
#define S_  2048
#define E_  300
#define H_  150
#define C_  34
#define CHUNK 128
#define NCHUNK (S_ / CHUNK)   // 16
#define WAVES 4               // 256-thread blocks

// Gather pass with online softmax, 4 tokens per group, 2-deep software
// pipeline: group g+1's 8 row loads are issued BEFORE group g's compute
// (dots + butterfly reduce + softmax), so HBM/L3 latency hides under the
// ~350-cycle compute chain. Accumulation order is bit-identical to the
// verified round-0 kernel (same groups, same order).
__global__ __launch_bounds__(256, 4) void attn_pass(
    const int* __restrict__ x, const float* __restrict__ emb,
    const float* __restrict__ qmat, int q_stride, float scale,
    float* __restrict__ h_part, float* __restrict__ m_part,
    float* __restrict__ l_part)
{
    const int b     = blockIdx.y;
    const int chunk = blockIdx.x;
    const int tid   = threadIdx.x;
    const int w     = tid >> 6;
    const int lane  = tid & 63;

    // Per-lane query fragment (pre-scaled): float4 slot `lane` + slot 64+lane
    const float4* qp = (const float4*)(qmat + (size_t)b * q_stride);
    float4 q0 = qp[lane];
    float4 q1 = make_float4(0.f, 0.f, 0.f, 0.f);
    if (lane < 11) q1 = qp[64 + lane];
    q0.x *= scale; q0.y *= scale; q0.z *= scale; q0.w *= scale;
    q1.x *= scale; q1.y *= scale; q1.z *= scale; q1.w *= scale;

    // Wave's 32 token indices live in lanes 0..31
    const int base = b * S_ + chunk * CHUNK;
    int myidx = 0;
    if (lane < 32) myidx = x[base + w + 4 * lane];

    float  m = -INFINITY, l = 0.f;
    float4 a0 = make_float4(0.f, 0.f, 0.f, 0.f);
    float4 a1 = make_float4(0.f, 0.f, 0.f, 0.f);

    // --- pipeline prologue: issue group 0's loads ---
    float4 r0[4], r1[4];
    #pragma unroll
    for (int t = 0; t < 4; ++t) {
        const int row = __shfl(myidx, t);
        const float4* rp = (const float4*)(emb + (size_t)row * E_);
        r0[t] = rp[lane];
        r1[t] = make_float4(0.f, 0.f, 0.f, 0.f);
        if (lane < 11) r1[t] = rp[64 + lane];
    }

    #pragma unroll
    for (int g = 0; g < 8; ++g) {
        // --- issue NEXT group's 8 loads first (stay in flight over compute) ---
        float4 n0[4], n1[4];
        if (g < 7) {
            #pragma unroll
            for (int t = 0; t < 4; ++t) {
                const int row = __shfl(myidx, 4 * (g + 1) + t);
                const float4* rp = (const float4*)(emb + (size_t)row * E_);
                n0[t] = rp[lane];
                n1[t] = make_float4(0.f, 0.f, 0.f, 0.f);
                if (lane < 11) n1[t] = rp[64 + lane];
            }
        }
        // --- 4 dots on CURRENT group (waits only on r0/r1's loads) ---
        float d[4];
        #pragma unroll
        for (int t = 0; t < 4; ++t)
            d[t] = q0.x * r0[t].x + q0.y * r0[t].y + q0.z * r0[t].z + q0.w * r0[t].w
                 + q1.x * r1[t].x + q1.y * r1[t].y + q1.z * r1[t].z + q1.w * r1[t].w;
        // --- 4 butterfly reduces, interleaved (independent DS chains) ---
        #pragma unroll
        for (int off = 32; off > 0; off >>= 1) {
            #pragma unroll
            for (int t = 0; t < 4; ++t) d[t] += __shfl_xor(d[t], off);
        }
        // --- branchless grouped online-softmax update ---
        const float gm = fmaxf(fmaxf(d[0], d[1]), fmaxf(d[2], d[3]));
        const float mn = fmaxf(m, gm);
        const float c  = __expf(m - mn);        // first group: exp(-inf)=0
        const float p0 = __expf(d[0] - mn), p1 = __expf(d[1] - mn);
        const float p2 = __expf(d[2] - mn), p3 = __expf(d[3] - mn);
        l = l * c + ((p0 + p1) + (p2 + p3));
        a0.x = a0.x * c + p0 * r0[0].x + p1 * r0[1].x + p2 * r0[2].x + p3 * r0[3].x;
        a0.y = a0.y * c + p0 * r0[0].y + p1 * r0[1].y + p2 * r0[2].y + p3 * r0[3].y;
        a0.z = a0.z * c + p0 * r0[0].z + p1 * r0[1].z + p2 * r0[2].z + p3 * r0[3].z;
        a0.w = a0.w * c + p0 * r0[0].w + p1 * r0[1].w + p2 * r0[2].w + p3 * r0[3].w;
        a1.x = a1.x * c + p0 * r1[0].x + p1 * r1[1].x + p2 * r1[2].x + p3 * r1[3].x;
        a1.y = a1.y * c + p0 * r1[0].y + p1 * r1[1].y + p2 * r1[2].y + p3 * r1[3].y;
        a1.z = a1.z * c + p0 * r1[0].z + p1 * r1[1].z + p2 * r1[2].z + p3 * r1[3].z;
        a1.w = a1.w * c + p0 * r1[0].w + p1 * r1[1].w + p2 * r1[2].w + p3 * r1[3].w;
        m = mn;
        // --- rotate pipeline registers (renamed away by regalloc) ---
        if (g < 7) {
            #pragma unroll
            for (int t = 0; t < 4; ++t) { r0[t] = n0[t]; r1[t] = n1[t]; }
        }
    }

    // Combine 4 waves in LDS
    __shared__ float sm[WAVES], sl[WAVES];
    __shared__ __align__(16) float sacc[WAVES][304];
    ((float4*)sacc[w])[lane] = a0;
    if (lane < 11) ((float4*)sacc[w])[64 + lane] = a1;
    if (lane == 0) { sm[w] = m; sl[w] = l; }
    __syncthreads();

    // E_=300 > 256 threads: must LOOP
    const float mb = fmaxf(fmaxf(sm[0], sm[1]), fmaxf(sm[2], sm[3]));
    const int pi = b * NCHUNK + chunk;
    for (int j = tid; j < E_; j += 256) {
        float h = 0.f;
        #pragma unroll
        for (int c = 0; c < WAVES; ++c)
            h += __expf(sm[c] - mb) * sacc[c][j];
        h_part[(size_t)pi * E_ + j] = h;
    }
    if (tid == 0) {
        float lb = 0.f;
        #pragma unroll
        for (int c = 0; c < WAVES; ++c) lb += __expf(sm[c] - mb) * sl[c];
        m_part[pi] = mb; l_part[pi] = lb;
    }
}

// Fused: combine NCHUNK partials -> h1[b], then v2[b] = (h1 @ W) @ W^T
__global__ __launch_bounds__(320) void combine_qv(
    const float* __restrict__ h_part, const float* __restrict__ m_part,
    const float* __restrict__ l_part, const float* __restrict__ W,
    float* __restrict__ h1out, float* __restrict__ v2out)
{
    const int b = blockIdx.x, tid = threadIdx.x;
    __shared__ float sm[NCHUNK], sl[NCHUNK], sh[E_], sq[H_];
    if (tid < NCHUNK) { sm[tid] = m_part[b * NCHUNK + tid];
                        sl[tid] = l_part[b * NCHUNK + tid]; }
    __syncthreads();
    if (tid < E_) {
        float M = -INFINITY;
        #pragma unroll
        for (int c = 0; c < NCHUNK; ++c) M = fmaxf(M, sm[c]);
        float L = 0.f, h = 0.f;
        #pragma unroll
        for (int c = 0; c < NCHUNK; ++c) {
            const float wc = __expf(sm[c] - M);
            L += wc * sl[c];
            h += wc * h_part[((size_t)b * NCHUNK + c) * E_ + tid];
        }
        const float v = h / L;
        sh[tid] = v;
        h1out[b * E_ + tid] = v;
    }
    __syncthreads();
    if (tid < H_) {
        float acc = 0.f;
        for (int e = 0; e < E_; ++e) acc += sh[e] * W[e * H_ + tid];
        sq[tid] = acc;
    }
    __syncthreads();
    if (tid < E_) {
        float acc = 0.f;
        const float* wr = W + (size_t)tid * H_;
        for (int h = 0; h < H_; ++h) acc += sq[h] * wr[h];
        v2out[b * E_ + tid] = acc;
    }
}

// Fused: combine NCHUNK partials -> h2[b], then scores = [h1;h2]@Wout + bias
__global__ __launch_bounds__(320) void combine_scores(
    const float* __restrict__ h_part, const float* __restrict__ m_part,
    const float* __restrict__ l_part, const float* __restrict__ h1,
    const float* __restrict__ Wout, const float* __restrict__ bias,
    float* __restrict__ out)
{
    const int b = blockIdx.x, tid = threadIdx.x;
    const int w = tid >> 6, lane = tid & 63;
    __shared__ float sm[NCHUNK], sl[NCHUNK];
    __shared__ float hh[2 * E_];
    if (tid < NCHUNK) { sm[tid] = m_part[b * NCHUNK + tid];
                        sl[tid] = l_part[b * NCHUNK + tid]; }
    if (tid < E_) hh[tid] = h1[b * E_ + tid];
    __syncthreads();
    if (tid < E_) {
        float M = -INFINITY;
        #pragma unroll
        for (int c = 0; c < NCHUNK; ++c) M = fmaxf(M, sm[c]);
        float L = 0.f, h = 0.f;
        #pragma unroll
        for (int c = 0; c < NCHUNK; ++c) {
            const float wc = __expf(sm[c] - M);
            L += wc * sl[c];
            h += wc * h_part[((size_t)b * NCHUNK + c) * E_ + tid];
        }
        hh[E_ + tid] = h / L;
    }
    __syncthreads();
    // 5 waves cover 34 classes
    for (int c = w; c < C_; c += 5) {
        float p = 0.f;
        for (int e = lane; e < 2 * E_; e += 64)
            p += hh[e] * Wout[(size_t)e * C_ + c];
        #pragma unroll
        for (int off = 32; off > 0; off >>= 1) p += __shfl_xor(p, off);
        if (lane == 0) out[b * C_ + c] = p + bias[c];
    }
}

extern "C" void kernel_launch(void* const* d_in, const int* in_sizes, int n_in,
                              void* d_out, int out_size, void* d_ws, size_t ws_size,
                              hipStream_t stream) {
    const int*   x     = (const int*)  d_in[0];   // [64,2048] int32
    const float* emb   = (const float*)d_in[1];   // [50000,300]
    const float* query = (const float*)d_in[2];   // [1,300]
    const float* Watt  = (const float*)d_in[3];   // [300,150]
    const float* Wout  = (const float*)d_in[4];   // [600,34]
    const float* bias  = (const float*)d_in[5];   // [34]
    float* out = (float*)d_out;                   // [64,34]

    // Workspace layout (floats)
    float* ws     = (float*)d_ws;
    float* h_part = ws;                                 // B*NCHUNK*E = 307200
    float* m_part = h_part + (size_t)B_ * NCHUNK * E_;  // 1024
    float* l_part = m_part + B_ * NCHUNK;               // 1024
    float* h1     = l_part + B_ * NCHUNK;               // 19200
    float* v2     = h1 + B_ * E_;                       // 19200

    const float scale1 = 1.0f / sqrtf((float)E_);
    dim3 grid(NCHUNK, B_), blk(256);

    // Stage 1: broadcast query (stride 0), scaled by 1/sqrt(E)
    attn_pass<<<grid, blk, 0, stream>>>(x, emb, query, 0, scale1,
                                        h_part, m_part, l_part);
    // h1 + v2 = (h1@W)@W^T in one 64-block kernel
    combine_qv<<<B_, 320, 0, stream>>>(h_part, m_part, l_part, Watt, h1, v2);
    // Stage 2: per-b query v2, no scale (reference has none)
    attn_pass<<<grid, blk, 0, stream>>>(x, emb, v2, E_, 1.0f,
                                        h_part, m_part, l_part);
    // h2 + final scores in one 64-block kernel
    combine_scores<<<B_, 320, 0, stream>>>(h_part, m_part, l_part, h1,
                                           Wout, bias, out);
}

// Round 3
// 187.907 us; speedup vs baseline: 2.7564x; 2.1180x over previous
//
#include <hip/hip_runtime.h>
#include <math.h>

// Problem constants (from reference)
#define B_  64
#define S_  2048
#define E_  300
#define H_  150
#define C_  34
#define CHUNK 128
#define NCHUNK (S_ / CHUNK)   // 16
#define WAVES 4               // 256-thread blocks

// Load group gi's 8 rows (4 tokens x 2 slots) into register buffers R0/R1.
#define LOADG(gi, R0, R1)                                                 \
  {                                                                       \
    _Pragma("unroll")                                                     \
    for (int t = 0; t < 4; ++t) {                                         \
      const int row_ = __shfl(myidx, 4 * (gi) + t);                       \
      const float4* rp_ = (const float4*)(emb + (size_t)row_ * E_);       \
      R0[t] = rp_[lane];                                                  \
      R1[t] = make_float4(0.f, 0.f, 0.f, 0.f);                           \
      if (lane < 11) R1[t] = rp_[64 + lane];                              \
    }                                                                     \
  }

// Dots + interleaved butterfly reduce + branchless grouped online softmax.
// Accumulation order identical to the verified round-0 kernel.
#define COMPUTEG(R0, R1)                                                  \
  {                                                                       \
    float d[4];                                                           \
    _Pragma("unroll")                                                     \
    for (int t = 0; t < 4; ++t)                                           \
      d[t] = q0.x * R0[t].x + q0.y * R0[t].y + q0.z * R0[t].z             \
           + q0.w * R0[t].w + q1.x * R1[t].x + q1.y * R1[t].y             \
           + q1.z * R1[t].z + q1.w * R1[t].w;                             \
    _Pragma("unroll")                                                     \
    for (int off = 32; off > 0; off >>= 1) {                              \
      _Pragma("unroll")                                                   \
      for (int t = 0; t < 4; ++t) d[t] += __shfl_xor(d[t], off);          \
    }                                                                     \
    const float gm = fmaxf(fmaxf(d[0], d[1]), fmaxf(d[2], d[3]));         \
    const float mn = fmaxf(m, gm);                                        \
    const float c  = __expf(m - mn);                                      \
    const float p0 = __expf(d[0] - mn), p1 = __expf(d[1] - mn);           \
    const float p2 = __expf(d[2] - mn), p3 = __expf(d[3] - mn);           \
    l = l * c + ((p0 + p1) + (p2 + p3));                                  \
    a0.x = a0.x * c + p0 * R0[0].x + p1 * R0[1].x + p2 * R0[2].x + p3 * R0[3].x; \
    a0.y = a0.y * c + p0 * R0[0].y + p1 * R0[1].y + p2 * R0[2].y + p3 * R0[3].y; \
    a0.z = a0.z * c + p0 * R0[0].z + p1 * R0[1].z + p2 * R0[2].z + p3 * R0[3].z; \
    a0.w = a0.w * c + p0 * R0[0].w + p1 * R0[1].w + p2 * R0[2].w + p3 * R0[3].w; \
    a1.x = a1.x * c + p0 * R1[0].x + p1 * R1[1].x + p2 * R1[2].x + p3 * R1[3].x; \
    a1.y = a1.y * c + p0 * R1[0].y + p1 * R1[1].y + p2 * R1[2].y + p3 * R1[3].y; \
    a1.z = a1.z * c + p0 * R1[0].z + p1 * R1[1].z + p2 * R1[2].z + p3 * R1[3].z; \
    a1.w = a1.w * c + p0 * R1[0].w + p1 * R1[1].w + p2 * R1[2].w + p3 * R1[3].w; \
    m = mn;                                                               \
  }

// Gather pass with online softmax, 4 tokens per group, 2-deep ping-pong
// pipeline. `#pragma unroll 1` on the pair loop stops the scheduler from
// hoisting loads beyond one group ahead (round-2 lesson: full unroll let it
// hoist ~64 float4 loads -> 235 MB of scratch spill traffic).
__global__ __launch_bounds__(256, 4) void attn_pass(
    const int* __restrict__ x, const float* __restrict__ emb,
    const float* __restrict__ qmat, int q_stride, float scale,
    float* __restrict__ h_part, float* __restrict__ m_part,
    float* __restrict__ l_part)
{
    const int b     = blockIdx.y;
    const int chunk = blockIdx.x;
    const int tid   = threadIdx.x;
    const int w     = tid >> 6;
    const int lane  = tid & 63;

    // Per-lane query fragment (pre-scaled): float4 slot `lane` + slot 64+lane
    const float4* qp = (const float4*)(qmat + (size_t)b * q_stride);
    float4 q0 = qp[lane];
    float4 q1 = make_float4(0.f, 0.f, 0.f, 0.f);
    if (lane < 11) q1 = qp[64 + lane];
    q0.x *= scale; q0.y *= scale; q0.z *= scale; q0.w *= scale;
    q1.x *= scale; q1.y *= scale; q1.z *= scale; q1.w *= scale;

    // Wave's 32 token indices live in lanes 0..31
    const int base = b * S_ + chunk * CHUNK;
    int myidx = 0;
    if (lane < 32) myidx = x[base + w + 4 * lane];

    float  m = -INFINITY, l = 0.f;
    float4 a0 = make_float4(0.f, 0.f, 0.f, 0.f);
    float4 a1 = make_float4(0.f, 0.f, 0.f, 0.f);

    float4 A0[4], A1[4], B0[4], B1[4];

    // Pipeline: load g; {load g+1; compute g; load g+2; compute g+1} x3;
    // load 7; compute 6; compute 7. Group order 0..7 = bit-identical math.
    LOADG(0, A0, A1);
    #pragma unroll 1
    for (int gg = 0; gg < 3; ++gg) {
        LOADG(2 * gg + 1, B0, B1);
        COMPUTEG(A0, A1);
        LOADG(2 * gg + 2, A0, A1);
        COMPUTEG(B0, B1);
    }
    LOADG(7, B0, B1);
    COMPUTEG(A0, A1);
    COMPUTEG(B0, B1);

    // Combine 4 waves in LDS
    __shared__ float sm[WAVES], sl[WAVES];
    __shared__ __align__(16) float sacc[WAVES][304];
    ((float4*)sacc[w])[lane] = a0;
    if (lane < 11) ((float4*)sacc[w])[64 + lane] = a1;
    if (lane == 0) { sm[w] = m; sl[w] = l; }
    __syncthreads();

    // E_=300 > 256 threads: must LOOP
    const float mb = fmaxf(fmaxf(sm[0], sm[1]), fmaxf(sm[2], sm[3]));
    const int pi = b * NCHUNK + chunk;
    for (int j = tid; j < E_; j += 256) {
        float h = 0.f;
        #pragma unroll
        for (int c = 0; c < WAVES; ++c)
            h += __expf(sm[c] - mb) * sacc[c][j];
        h_part[(size_t)pi * E_ + j] = h;
    }
    if (tid == 0) {
        float lb = 0.f;
        #pragma unroll
        for (int c = 0; c < WAVES; ++c) lb += __expf(sm[c] - mb) * sl[c];
        m_part[pi] = mb; l_part[pi] = lb;
    }
}

// Fused: combine NCHUNK partials -> h1[b], then v2[b] = (h1 @ W) @ W^T
__global__ __launch_bounds__(320) void combine_qv(
    const float* __restrict__ h_part, const float* __restrict__ m_part,
    const float* __restrict__ l_part, const float* __restrict__ W,
    float* __restrict__ h1out, float* __restrict__ v2out)
{
    const int b = blockIdx.x, tid = threadIdx.x;
    __shared__ float sm[NCHUNK], sl[NCHUNK], sh[E_], sq[H_];
    if (tid < NCHUNK) { sm[tid] = m_part[b * NCHUNK + tid];
                        sl[tid] = l_part[b * NCHUNK + tid]; }
    __syncthreads();
    if (tid < E_) {
        float M = -INFINITY;
        #pragma unroll
        for (int c = 0; c < NCHUNK; ++c) M = fmaxf(M, sm[c]);
        float L = 0.f, h = 0.f;
        #pragma unroll
        for (int c = 0; c < NCHUNK; ++c) {
            const float wc = __expf(sm[c] - M);
            L += wc * sl[c];
            h += wc * h_part[((size_t)b * NCHUNK + c) * E_ + tid];
        }
        const float v = h / L;
        sh[tid] = v;
        h1out[b * E_ + tid] = v;
    }
    __syncthreads();
    if (tid < H_) {
        float acc = 0.f;
        for (int e = 0; e < E_; ++e) acc += sh[e] * W[e * H_ + tid];
        sq[tid] = acc;
    }
    __syncthreads();
    if (tid < E_) {
        float acc = 0.f;
        const float* wr = W + (size_t)tid * H_;
        for (int h = 0; h < H_; ++h) acc += sq[h] * wr[h];
        v2out[b * E_ + tid] = acc;
    }
}

// Fused: combine NCHUNK partials -> h2[b], then scores = [h1;h2]@Wout + bias
__global__ __launch_bounds__(320) void combine_scores(
    const float* __restrict__ h_part, const float* __restrict__ m_part,
    const float* __restrict__ l_part, const float* __restrict__ h1,
    const float* __restrict__ Wout, const float* __restrict__ bias,
    float* __restrict__ out)
{
    const int b = blockIdx.x, tid = threadIdx.x;
    const int w = tid >> 6, lane = tid & 63;
    __shared__ float sm[NCHUNK], sl[NCHUNK];
    __shared__ float hh[2 * E_];
    if (tid < NCHUNK) { sm[tid] = m_part[b * NCHUNK + tid];
                        sl[tid] = l_part[b * NCHUNK + tid]; }
    if (tid < E_) hh[tid] = h1[b * E_ + tid];
    __syncthreads();
    if (tid < E_) {
        float M = -INFINITY;
        #pragma unroll
        for (int c = 0; c < NCHUNK; ++c) M = fmaxf(M, sm[c]);
        float L = 0.f, h = 0.f;
        #pragma unroll
        for (int c = 0; c < NCHUNK; ++c) {
            const float wc = __expf(sm[c] - M);
            L += wc * sl[c];
            h += wc * h_part[((size_t)b * NCHUNK + c) * E_ + tid];
        }
        hh[E_ + tid] = h / L;
    }
    __syncthreads();
    // 5 waves cover 34 classes
    for (int c = w; c < C_; c += 5) {
        float p = 0.f;
        for (int e = lane; e < 2 * E_; e += 64)
            p += hh[e] * Wout[(size_t)e * C_ + c];
        #pragma unroll
        for (int off = 32; off > 0; off >>= 1) p += __shfl_xor(p, off);
        if (lane == 0) out[b * C_ + c] = p + bias[c];
    }
}

extern "C" void kernel_launch(void* const* d_in, const int* in_sizes, int n_in,
                              void* d_out, int out_size, void* d_ws, size_t ws_size,
                              hipStream_t stream) {
    const int*   x     = (const int*)  d_in[0];   // [64,2048] int32
    const float* emb   = (const float*)d_in[1];   // [50000,300]
    const float* query = (const float*)d_in[2];   // [1,300]
    const float* Watt  = (const float*)d_in[3];   // [300,150]
    const float* Wout  = (const float*)d_in[4];   // [600,34]
    const float* bias  = (const float*)d_in[5];   // [34]
    float* out = (float*)d_out;                   // [64,34]

    // Workspace layout (floats)
    float* ws     = (float*)d_ws;
    float* h_part = ws;                                 // B*NCHUNK*E = 307200
    float* m_part = h_part + (size_t)B_ * NCHUNK * E_;  // 1024
    float* l_part = m_part + B_ * NCHUNK;               // 1024
    float* h1     = l_part + B_ * NCHUNK;               // 19200
    float* v2     = h1 + B_ * E_;                       // 19200

    const float scale1 = 1.0f / sqrtf((float)E_);
    dim3 grid(NCHUNK, B_), blk(256);

    // Stage 1: broadcast query (stride 0), scaled by 1/sqrt(E)
    attn_pass<<<grid, blk, 0, stream>>>(x, emb, query, 0, scale1,
                                        h_part, m_part, l_part);
    // h1 + v2 = (h1@W)@W^T in one 64-block kernel
    combine_qv<<<B_, 320, 0, stream>>>(h_part, m_part, l_part, Watt, h1, v2);
    // Stage 2: per-b query v2, no scale (reference has none)
    attn_pass<<<grid, blk, 0, stream>>>(x, emb, v2, E_, 1.0f,
                                        h_part, m_part, l_part);
    // h2 + final scores in one 64-block kernel
    combine_scores<<<B_, 320, 0, stream>>>(h_part, m_part, l_part, h1,
                                           Wout, bias, out);
}